// Round 13
// baseline (260.553 us; speedup 1.0000x reference)
//
#include <hip/hip_runtime.h>
#include <math.h>
#include <float.h>

// Fixed instance: B=8, D=256, N=2048
#define BB 8
#define DDIM 256
#define NN 2048
#define MSPLIT 8            // 2048 / 256 = 8 m-tiles

typedef _Float16 half8 __attribute__((ext_vector_type(8)));
typedef float f32x16 __attribute__((ext_vector_type(16)));
typedef unsigned u32;
typedef unsigned long long u64;

__device__ __forceinline__ u32 umin32(u32 a, u32 b) { return a < b ? a : b; }
__device__ __forceinline__ u32 umax32(u32 a, u32 b) { return a > b ? a : b; }
__device__ __forceinline__ u64 umin64(u64 a, u64 b) { return a < b ? a : b; }
__device__ __forceinline__ u64 umax64(u64 a, u64 b) { return a > b ? a : b; }

// Async global->LDS, 16B per lane.
__device__ __forceinline__ void gload16(const void* g, void* l) {
    __builtin_amdgcn_global_load_lds((const __attribute__((address_space(1))) void*)g,
                                     (__attribute__((address_space(3))) void*)l,
                                     16, 0, 0);
}

// ---------------------------------------------------------------------------
// Pre-kernel, x16 PROBE this round: body repeated 16x with an opaque-zero
// pointer offset per rep (defeats load-hoist + dead-store elim; reps are
// idempotent -> output byte-identical). Dispatch dur ~= 16x real pre time ->
// enters rocprof top-5 with counters.
// ---------------------------------------------------------------------------
__global__ __launch_bounds__(256) void pre_kernel(const float* __restrict__ x,
                                                  _Float16* __restrict__ xh,
                                                  double* __restrict__ sq64,
                                                  float* __restrict__ sqf) {
    __shared__ double lds[4][64];
    const int b = blockIdx.y;
    const int n0 = blockIdx.x * 64;
    const int t = threadIdx.x;
    const int c4 = t & 3;
    const int r = t >> 2;
    const int n = n0 + r;

#pragma unroll 1
    for (int rep = 0; rep < 16; ++rep) {
        int z = 0;
        asm volatile("" : "+v"(z));          // opaque 0: re-emit loads/stores
        const float* xz = x + z;
        _Float16* xhz = xh + z;

        double s = 0.0;
#pragma unroll
        for (int dt = 0; dt < 4; ++dt) {
            const int db = dt * 64 + c4 * 16;
            const float* xp = xz + ((size_t)b * DDIM + db) * NN + n;
            float v[16];
#pragma unroll
            for (int q = 0; q < 16; ++q) v[q] = xp[(size_t)q * NN];

            half8 h0, h1;
#pragma unroll
            for (int q = 0; q < 8; ++q) { h0[q] = (_Float16)v[q];     s += (double)v[q] * v[q]; }
#pragma unroll
            for (int q = 0; q < 8; ++q) { h1[q] = (_Float16)v[8 + q]; s += (double)v[8 + q] * v[8 + q]; }

            const size_t o = ((size_t)b * NN + n) * DDIM + db;
            *(half8*)&xhz[o]     = h0;
            *(half8*)&xhz[o + 8] = h1;
        }

        lds[c4][r] = s;
        __syncthreads();
        if (c4 == 0) {
            const double sum = lds[0][r] + lds[1][r] + lds[2][r] + lds[3][r];
            sq64[(b * NN + n) + z] = sum;
            sqf[(b * NN + n) + z] = (float)sum;
        }
        __syncthreads();                     // lds reused next rep
    }
}

// ---------------------------------------------------------------------------
// Epilogue scan (R6 version): per-column top-2 over this wave's 128 m-rows.
// ---------------------------------------------------------------------------
template<bool DIAG>
__device__ __forceinline__ void epi_scan(const f32x16 (&acc)[4][2],
                                         const float* __restrict__ sqm_g,
                                         int wm, int l, int delta0,
                                         u32 (&k1a)[2], u32 (&k2a)[2]) {
#pragma unroll
    for (int i = 0; i < 4; ++i) {
        const int mbase = wm * 128 + i * 32 + ((l >> 5) << 2);
        const float4 s0 = *(const float4*)&sqm_g[mbase];
        const float4 s1 = *(const float4*)&sqm_g[mbase + 8];
        const float4 s2 = *(const float4*)&sqm_g[mbase + 16];
        const float4 s3 = *(const float4*)&sqm_g[mbase + 24];
        const float svp[16] = {512.0f + s0.x, 512.0f + s0.y, 512.0f + s0.z, 512.0f + s0.w,
                               512.0f + s1.x, 512.0f + s1.y, 512.0f + s1.z, 512.0f + s1.w,
                               512.0f + s2.x, 512.0f + s2.y, 512.0f + s2.z, 512.0f + s2.w,
                               512.0f + s3.x, 512.0f + s3.y, 512.0f + s3.z, 512.0f + s3.w};
#pragma unroll
        for (int j = 0; j < 2; ++j) {
            const int delta = delta0 + j * 32;
#pragma unroll
            for (int r = 0; r < 16; ++r) {
                const int mloc = mbase + (r & 3) + ((r >> 2) << 3);
                const float v = fmaxf(fmaf(-2.0f, acc[i][j][r], svp[r]), 0.0f);
                u32 key = (__float_as_uint(v) & 0xffffff00u) | (u32)mloc;
                if constexpr (DIAG) key = (mloc == delta) ? 0xffffffffu : key;
                const u32 t = umax32(k1a[j], key);
                k1a[j] = umin32(k1a[j], key);
                k2a[j] = umin32(k2a[j], t);
            }
        }
    }
}

// ---------------------------------------------------------------------------
// Gram + per-column top-2 — EXACT R6 structure (best measured: gram 24.6 us,
// total 48.2): 256x256 tile, 8 waves 2x4, wave tile 128x64 via 4x2
// mfma_f32_32x32x16_f16, BK=64 double-buffered 128 KB dynamic LDS, 2-barrier
// loop, chunk^(row&7) swizzle both-sides, batch-fastest XCD pinning.
// ---------------------------------------------------------------------------
__global__ __launch_bounds__(512, 2) void gram_topk_kernel(const _Float16* __restrict__ xh,
                                                           const float* __restrict__ sqf,
                                                           u32* __restrict__ gk1,
                                                           u32* __restrict__ gk2) {
    extern __shared__ _Float16 smem[];   // 131072 B: A[2][256][64] | B[2][256][64]

    const int id = blockIdx.x;
    const int b  = id & 7;
    const int mt = (id >> 3) & 7;
    const int nt = id >> 6;
    const int m0 = mt << 8, n0 = nt << 8;
    const int tid = threadIdx.x;
    const int l = tid & 63;
    const int w = tid >> 6;
    const int wm = w >> 2, wn = w & 3;

    const _Float16* xb = xh + (size_t)b * NN * DDIM;

    const int srl  = l >> 3;
    const int sswz = (l & 7) ^ srl;

#define STAGE(kt, bufi)                                                          \
    {                                                                            \
        const int kb_ = (kt) * 64 + sswz * 8;                                    \
        _Float16* abase_ = smem + (bufi) * 16384;                                \
        _Float16* bbase_ = smem + 32768 + (bufi) * 16384;                        \
        _Pragma("unroll")                                                        \
        for (int i8 = 0; i8 < 4; ++i8) {                                         \
            const int r0_ = w * 32 + i8 * 8;                                     \
            gload16(xb + (size_t)(m0 + r0_ + srl) * DDIM + kb_, abase_ + r0_ * 64); \
            gload16(xb + (size_t)(n0 + r0_ + srl) * DDIM + kb_, bbase_ + r0_ * 64); \
        }                                                                        \
    }

    f32x16 acc[4][2];
#pragma unroll
    for (int i = 0; i < 4; ++i)
#pragma unroll
        for (int j = 0; j < 2; ++j)
#pragma unroll
            for (int r = 0; r < 16; ++r) acc[i][j][r] = 0.0f;

    int buf = 0;
    STAGE(0, 0);
    __syncthreads();

#pragma unroll
    for (int kt = 0; kt < 4; ++kt) {
        if (kt < 3) STAGE(kt + 1, buf ^ 1);
        const int boff = buf * 16384;
#pragma unroll
        for (int ks = 0; ks < 4; ++ks) {
            const int ch = 2 * ks + (l >> 5);
            half8 a[4], bv[2];
#pragma unroll
            for (int i = 0; i < 4; ++i) {
                const int lrow = wm * 128 + i * 32 + (l & 31);
                const int chunk = ch ^ (lrow & 7);
                a[i] = *(const half8*)&smem[boff + lrow * 64 + chunk * 8];
            }
#pragma unroll
            for (int j = 0; j < 2; ++j) {
                const int lrow = wn * 64 + j * 32 + (l & 31);
                const int chunk = ch ^ (lrow & 7);
                bv[j] = *(const half8*)&smem[32768 + boff + lrow * 64 + chunk * 8];
            }
#pragma unroll
            for (int i = 0; i < 4; ++i)
#pragma unroll
                for (int j = 0; j < 2; ++j)
                    acc[i][j] = __builtin_amdgcn_mfma_f32_32x32x16_f16(a[i], bv[j], acc[i][j], 0, 0, 0);
        }
        if (kt < 3) { __syncthreads(); buf ^= 1; }
    }
#undef STAGE

    __syncthreads();
    u32* mbuf = (u32*)smem;

    const float* sqm_g = sqf + b * NN + m0;
    u32 k1a[2] = {0xffffffffu, 0xffffffffu};
    u32 k2a[2] = {0xffffffffu, 0xffffffffu};
    const int delta0 = n0 + wn * 64 + (l & 31) - m0;
    if (mt == nt) epi_scan<true >(acc, sqm_g, wm, l, delta0, k1a, k2a);
    else          epi_scan<false>(acc, sqm_g, wm, l, delta0, k1a, k2a);

    u32 K1[2], K2[2];
#pragma unroll
    for (int j = 0; j < 2; ++j) {
        const u32 o1 = __shfl_xor(k1a[j], 32);
        const u32 o2 = __shfl_xor(k2a[j], 32);
        K1[j] = umin32(k1a[j], o1);
        K2[j] = umin32(umax32(k1a[j], o1), umin32(k2a[j], o2));
    }

    if (wm == 1 && l < 32) {
#pragma unroll
        for (int j = 0; j < 2; ++j) {
            const int c = wn * 64 + j * 32 + l;
            mbuf[c * 2]     = K1[j];
            mbuf[c * 2 + 1] = K2[j];
        }
    }
    __syncthreads();
    if (wm == 0 && l < 32) {
#pragma unroll
        for (int j = 0; j < 2; ++j) {
            const int c = wn * 64 + j * 32 + l;
            const u32 o1 = mbuf[c * 2];
            const u32 o2 = mbuf[c * 2 + 1];
            const u32 n1 = umin32(K1[j], o1);
            const u32 n2 = umin32(umax32(K1[j], o1), umin32(K2[j], o2));
            const size_t base = ((size_t)(b * NN + n0 + c) << 3) + mt;
            gk1[base] = n1;
            gk2[base] = n2;
        }
    }
}

// ---------------------------------------------------------------------------
// Fused tail, x16 PROBE this round (same opaque-zero technique; idempotent;
// fcnt reset + barrier at rep top makes rep boundaries race-free).
// ---------------------------------------------------------------------------
__global__ __launch_bounds__(256) void tail_kernel(const u32* __restrict__ gk1,
                                                   const u32* __restrict__ gk2,
                                                   const double* __restrict__ sq64,
                                                   const float* __restrict__ x,
                                                   const _Float16* __restrict__ xh,
                                                   const float* __restrict__ emb,
                                                   float* __restrict__ out) {
    __shared__ float embs[64][257];
    __shared__ float xs[64][257];
    __shared__ int   angs[64];
    __shared__ int   flist[64][3];
    __shared__ int   fcnt;

    const int b  = blockIdx.y;
    const int n0 = blockIdx.x * 64;
    const int t  = threadIdx.x;
    const int w  = t >> 6, l = t & 63;

#pragma unroll 1
    for (int rep = 0; rep < 16; ++rep) {
        int z = 0;
        asm volatile("" : "+v"(z));          // opaque 0
        const u32* gk1z = gk1 + z;
        const u32* gk2z = gk2 + z;
        const float* xz = x + z;
        const _Float16* xhz = xh + z;
        const float* embz = emb + z;
        float* outz = out + z;

        if (t == 0) fcnt = 0;
        __syncthreads();                     // also orders prev rep's phase 3b

        // ---- 1) per-row slot merge ----
        if (t < 64) {
            const int n = n0 + t;
            const int tg = (b << 11) + n;
            const uint4 a0 = *(const uint4*)&gk1z[(size_t)tg << 3];
            const uint4 a1 = *(const uint4*)&gk1z[((size_t)tg << 3) + 4];
            const uint4 c0 = *(const uint4*)&gk2z[(size_t)tg << 3];
            const uint4 c1 = *(const uint4*)&gk2z[((size_t)tg << 3) + 4];
            const u32 ga[8] = {a0.x, a0.y, a0.z, a0.w, a1.x, a1.y, a1.z, a1.w};
            const u32 gc[8] = {c0.x, c0.y, c0.z, c0.w, c1.x, c1.y, c1.z, c1.w};
            u64 k1 = ~0ull, k2 = ~0ull;
#pragma unroll
            for (int s = 0; s < MSPLIT; ++s) {
                const u64 ka = ((u64)(ga[s] >> 8) << 11) | (u32)((s << 8) | (ga[s] & 0xff));
                const u64 kc = ((u64)(gc[s] >> 8) << 11) | (u32)((s << 8) | (gc[s] & 0xff));
                const u64 n1 = umin64(k1, ka);
                const u64 n2 = umin64(umax64(k1, ka), umin64(k2, kc));
                k1 = n1; k2 = n2;
            }
            const int i1 = (int)(k1 & 0x7ff);
            const int i2 = (int)(k2 & 0x7ff);
            const float v1 = __uint_as_float((u32)(k1 >> 11) << 8);
            const float v2 = __uint_as_float((u32)(k2 >> 11) << 8);
            const int a = n - i1;
            angs[t] = a < 0 ? -a : a;
            if (v2 - v1 < 0.25f) {
                const int s = atomicAdd(&fcnt, 1);
                flist[s][0] = t; flist[s][1] = i1; flist[s][2] = i2;
            }
        }
        __syncthreads();

        // ---- 2) exact f64 re-rank of flagged rows ----
        const int nf = fcnt;
        const float* xb = xz + (size_t)b * DDIM * NN;
        for (int it = w; it < nf; it += 4) {
            const int rl = flist[it][0], i1 = flist[it][1], i2 = flist[it][2];
            const int n = n0 + rl;
            double d1 = 0.0, d2 = 0.0;
#pragma unroll
            for (int q = 0; q < 4; ++q) {
                const int d = l * 4 + q;
                const double xn = xb[(size_t)d * NN + n];
                d1 += xn * (double)xb[(size_t)d * NN + i1];
                d2 += xn * (double)xb[(size_t)d * NN + i2];
            }
#pragma unroll
            for (int off = 32; off; off >>= 1) {
                d1 += __shfl_down(d1, off);
                d2 += __shfl_down(d2, off);
            }
            if (l == 0) {
                const double sn = sq64[(b << 11) + n];
                double e1 = sn + sq64[(b << 11) + i1] - 2.0 * d1; if (e1 < 0.0) e1 = 0.0;
                double e2 = sn + sq64[(b << 11) + i2] - 2.0 * d2; if (e2 < 0.0) e2 = 0.0;
                const int best = (e2 < e1 || (e2 == e1 && i2 < i1)) ? i2 : i1;
                const int a = n - best;
                angs[rl] = a < 0 ? -a : a;
            }
        }
        __syncthreads();

        // ---- 3a) stage emb + xh rows coalesced ----
        const _Float16* xhb = xhz + ((size_t)b * NN + n0) * DDIM;
        for (int rr = w; rr < 64; rr += 4) {
            const int ang = angs[rr];
            const float4 ev = *(const float4*)&embz[(size_t)ang * DDIM + l * 4];
            embs[rr][l * 4]     = ev.x;
            embs[rr][l * 4 + 1] = ev.y;
            embs[rr][l * 4 + 2] = ev.z;
            embs[rr][l * 4 + 3] = ev.w;
            const ushort4 hv = *(const ushort4*)&xhb[(size_t)rr * DDIM + l * 4];
            xs[rr][l * 4]     = (float)*(const _Float16*)&hv.x;
            xs[rr][l * 4 + 1] = (float)*(const _Float16*)&hv.y;
            xs[rr][l * 4 + 2] = (float)*(const _Float16*)&hv.z;
            xs[rr][l * 4 + 3] = (float)*(const _Float16*)&hv.w;
        }
        __syncthreads();

        // ---- 3b) output ----
        const int ng = (t & 15) * 4;
        const int dr = t >> 4;
#pragma unroll
        for (int it = 0; it < 16; ++it) {
            const int d = it * 16 + dr;
            const size_t o = ((size_t)b * DDIM + d) * NN + n0 + ng;
            float4 ov;
            ov.x = xs[ng][d]     + embs[ng][d];
            ov.y = xs[ng + 1][d] + embs[ng + 1][d];
            ov.z = xs[ng + 2][d] + embs[ng + 2][d];
            ov.w = xs[ng + 3][d] + embs[ng + 3][d];
            *(float4*)&outz[o] = ov;
        }
        __syncthreads();                     // LDS reused next rep
    }
}

extern "C" void kernel_launch(void* const* d_in, const int* in_sizes, int n_in,
                              void* d_out, int out_size, void* d_ws, size_t ws_size,
                              hipStream_t stream) {
    const float* x   = (const float*)d_in[0];   // (B, D, N) f32
    const float* emb = (const float*)d_in[1];   // (N, D)    f32
    float* out = (float*)d_out;

    // Workspace carve-up (~9.6 MB total)
    char* ws = (char*)d_ws;
    _Float16* xh   = (_Float16*)ws;                    // 8,388,608 B
    u32*      gk1  = (u32*)(ws + 8388608);             //   524,288 B
    u32*      gk2  = (u32*)(ws + 8912896);             //   524,288 B
    double*   sq64 = (double*)(ws + 9437184);          //   131,072 B
    float*    sqf  = (float*)(ws + 9568256);           //    65,536 B

    // 128 KB dynamic LDS needs the attribute raised (host-side, capture-safe).
    hipFuncSetAttribute(reinterpret_cast<const void*>(gram_topk_kernel),
                        hipFuncAttributeMaxDynamicSharedMemorySize, 131072);

    pre_kernel<<<dim3(32, 8), dim3(256), 0, stream>>>(x, xh, sq64, sqf);
    gram_topk_kernel<<<dim3(512), dim3(512), 131072, stream>>>(xh, sqf, gk1, gk2);
    tail_kernel<<<dim3(32, 8), dim3(256), 0, stream>>>(gk1, gk2, sq64, x, xh, emb, out);
}

// Round 14
// 48.500 us; speedup vs baseline: 5.3722x; 5.3722x over previous
//
#include <hip/hip_runtime.h>
#include <math.h>
#include <float.h>

// Fixed instance: B=8, D=256, N=2048
#define BB 8
#define DDIM 256
#define NN 2048
#define MSPLIT 8            // 2048 / 256 = 8 m-tiles

typedef _Float16 half8 __attribute__((ext_vector_type(8)));
typedef float f32x16 __attribute__((ext_vector_type(16)));
typedef unsigned u32;
typedef unsigned long long u64;

__device__ __forceinline__ u32 umin32(u32 a, u32 b) { return a < b ? a : b; }
__device__ __forceinline__ u32 umax32(u32 a, u32 b) { return a > b ? a : b; }
__device__ __forceinline__ u64 umin64(u64 a, u64 b) { return a < b ? a : b; }
__device__ __forceinline__ u64 umax64(u64 a, u64 b) { return a > b ? a : b; }

// Async global->LDS, 16B per lane.
__device__ __forceinline__ void gload16(const void* g, void* l) {
    __builtin_amdgcn_global_load_lds((const __attribute__((address_space(1))) void*)g,
                                     (__attribute__((address_space(3))) void*)l,
                                     16, 0, 0);
}

// ---------------------------------------------------------------------------
// Pre-kernel (single-pass, R12 version): x (B,D,N) f32 -> xh (B,N,D) f16,
// fused full-D sum-of-squares in f64. Measured ~2.8 us (R13 probe bound).
// ---------------------------------------------------------------------------
__global__ __launch_bounds__(256) void pre_kernel(const float* __restrict__ x,
                                                  _Float16* __restrict__ xh,
                                                  double* __restrict__ sq64,
                                                  float* __restrict__ sqf) {
    __shared__ double lds[4][64];
    const int b = blockIdx.y;
    const int n0 = blockIdx.x * 64;
    const int t = threadIdx.x;
    const int c4 = t & 3;
    const int r = t >> 2;
    const int n = n0 + r;

    double s = 0.0;
#pragma unroll
    for (int dt = 0; dt < 4; ++dt) {
        const int db = dt * 64 + c4 * 16;
        const float* xp = x + ((size_t)b * DDIM + db) * NN + n;
        float v[16];
#pragma unroll
        for (int q = 0; q < 16; ++q) v[q] = xp[(size_t)q * NN];

        half8 h0, h1;
#pragma unroll
        for (int q = 0; q < 8; ++q) { h0[q] = (_Float16)v[q];     s += (double)v[q] * v[q]; }
#pragma unroll
        for (int q = 0; q < 8; ++q) { h1[q] = (_Float16)v[8 + q]; s += (double)v[8 + q] * v[8 + q]; }

        const size_t o = ((size_t)b * NN + n) * DDIM + db;
        *(half8*)&xh[o]     = h0;
        *(half8*)&xh[o + 8] = h1;
    }

    lds[c4][r] = s;
    __syncthreads();
    if (c4 == 0) {
        const double sum = lds[0][r] + lds[1][r] + lds[2][r] + lds[3][r];
        sq64[b * NN + n] = sum;
        sqf[b * NN + n] = (float)sum;
    }
}

// ---------------------------------------------------------------------------
// Epilogue scan (R6 version): per-column top-2 over this wave's 128 m-rows.
// ---------------------------------------------------------------------------
template<bool DIAG>
__device__ __forceinline__ void epi_scan(const f32x16 (&acc)[4][2],
                                         const float* __restrict__ sqm_g,
                                         int wm, int l, int delta0,
                                         u32 (&k1a)[2], u32 (&k2a)[2]) {
#pragma unroll
    for (int i = 0; i < 4; ++i) {
        const int mbase = wm * 128 + i * 32 + ((l >> 5) << 2);
        const float4 s0 = *(const float4*)&sqm_g[mbase];
        const float4 s1 = *(const float4*)&sqm_g[mbase + 8];
        const float4 s2 = *(const float4*)&sqm_g[mbase + 16];
        const float4 s3 = *(const float4*)&sqm_g[mbase + 24];
        const float svp[16] = {512.0f + s0.x, 512.0f + s0.y, 512.0f + s0.z, 512.0f + s0.w,
                               512.0f + s1.x, 512.0f + s1.y, 512.0f + s1.z, 512.0f + s1.w,
                               512.0f + s2.x, 512.0f + s2.y, 512.0f + s2.z, 512.0f + s2.w,
                               512.0f + s3.x, 512.0f + s3.y, 512.0f + s3.z, 512.0f + s3.w};
#pragma unroll
        for (int j = 0; j < 2; ++j) {
            const int delta = delta0 + j * 32;
#pragma unroll
            for (int r = 0; r < 16; ++r) {
                const int mloc = mbase + (r & 3) + ((r >> 2) << 3);
                const float v = fmaxf(fmaf(-2.0f, acc[i][j][r], svp[r]), 0.0f);
                u32 key = (__float_as_uint(v) & 0xffffff00u) | (u32)mloc;
                if constexpr (DIAG) key = (mloc == delta) ? 0xffffffffu : key;
                const u32 t = umax32(k1a[j], key);
                k1a[j] = umin32(k1a[j], key);
                k2a[j] = umin32(k2a[j], t);
            }
        }
    }
}

// ---------------------------------------------------------------------------
// Gram + per-column top-2 — EXACT R6 structure (best measured: 24.6 us):
// 256x256 tile, 8 waves 2x4, wave tile 128x64 via 4x2 mfma_f32_32x32x16_f16,
// BK=64 double-buffered 128 KB dynamic LDS, 2-barrier loop, chunk^(row&7)
// swizzle both-sides, batch-fastest XCD pinning.
// ---------------------------------------------------------------------------
__global__ __launch_bounds__(512, 2) void gram_topk_kernel(const _Float16* __restrict__ xh,
                                                           const float* __restrict__ sqf,
                                                           u32* __restrict__ gk1,
                                                           u32* __restrict__ gk2) {
    extern __shared__ _Float16 smem[];   // 131072 B: A[2][256][64] | B[2][256][64]

    const int id = blockIdx.x;
    const int b  = id & 7;
    const int mt = (id >> 3) & 7;
    const int nt = id >> 6;
    const int m0 = mt << 8, n0 = nt << 8;
    const int tid = threadIdx.x;
    const int l = tid & 63;
    const int w = tid >> 6;
    const int wm = w >> 2, wn = w & 3;

    const _Float16* xb = xh + (size_t)b * NN * DDIM;

    const int srl  = l >> 3;
    const int sswz = (l & 7) ^ srl;

#define STAGE(kt, bufi)                                                          \
    {                                                                            \
        const int kb_ = (kt) * 64 + sswz * 8;                                    \
        _Float16* abase_ = smem + (bufi) * 16384;                                \
        _Float16* bbase_ = smem + 32768 + (bufi) * 16384;                        \
        _Pragma("unroll")                                                        \
        for (int i8 = 0; i8 < 4; ++i8) {                                         \
            const int r0_ = w * 32 + i8 * 8;                                     \
            gload16(xb + (size_t)(m0 + r0_ + srl) * DDIM + kb_, abase_ + r0_ * 64); \
            gload16(xb + (size_t)(n0 + r0_ + srl) * DDIM + kb_, bbase_ + r0_ * 64); \
        }                                                                        \
    }

    f32x16 acc[4][2];
#pragma unroll
    for (int i = 0; i < 4; ++i)
#pragma unroll
        for (int j = 0; j < 2; ++j)
#pragma unroll
            for (int r = 0; r < 16; ++r) acc[i][j][r] = 0.0f;

    int buf = 0;
    STAGE(0, 0);
    __syncthreads();

#pragma unroll
    for (int kt = 0; kt < 4; ++kt) {
        if (kt < 3) STAGE(kt + 1, buf ^ 1);
        const int boff = buf * 16384;
#pragma unroll
        for (int ks = 0; ks < 4; ++ks) {
            const int ch = 2 * ks + (l >> 5);
            half8 a[4], bv[2];
#pragma unroll
            for (int i = 0; i < 4; ++i) {
                const int lrow = wm * 128 + i * 32 + (l & 31);
                const int chunk = ch ^ (lrow & 7);
                a[i] = *(const half8*)&smem[boff + lrow * 64 + chunk * 8];
            }
#pragma unroll
            for (int j = 0; j < 2; ++j) {
                const int lrow = wn * 64 + j * 32 + (l & 31);
                const int chunk = ch ^ (lrow & 7);
                bv[j] = *(const half8*)&smem[32768 + boff + lrow * 64 + chunk * 8];
            }
#pragma unroll
            for (int i = 0; i < 4; ++i)
#pragma unroll
                for (int j = 0; j < 2; ++j)
                    acc[i][j] = __builtin_amdgcn_mfma_f32_32x32x16_f16(a[i], bv[j], acc[i][j], 0, 0, 0);
        }
        if (kt < 3) { __syncthreads(); buf ^= 1; }
    }
#undef STAGE

    __syncthreads();
    u32* mbuf = (u32*)smem;

    const float* sqm_g = sqf + b * NN + m0;
    u32 k1a[2] = {0xffffffffu, 0xffffffffu};
    u32 k2a[2] = {0xffffffffu, 0xffffffffu};
    const int delta0 = n0 + wn * 64 + (l & 31) - m0;
    if (mt == nt) epi_scan<true >(acc, sqm_g, wm, l, delta0, k1a, k2a);
    else          epi_scan<false>(acc, sqm_g, wm, l, delta0, k1a, k2a);

    u32 K1[2], K2[2];
#pragma unroll
    for (int j = 0; j < 2; ++j) {
        const u32 o1 = __shfl_xor(k1a[j], 32);
        const u32 o2 = __shfl_xor(k2a[j], 32);
        K1[j] = umin32(k1a[j], o1);
        K2[j] = umin32(umax32(k1a[j], o1), umin32(k2a[j], o2));
    }

    if (wm == 1 && l < 32) {
#pragma unroll
        for (int j = 0; j < 2; ++j) {
            const int c = wn * 64 + j * 32 + l;
            mbuf[c * 2]     = K1[j];
            mbuf[c * 2 + 1] = K2[j];
        }
    }
    __syncthreads();
    if (wm == 0 && l < 32) {
#pragma unroll
        for (int j = 0; j < 2; ++j) {
            const int c = wn * 64 + j * 32 + l;
            const u32 o1 = mbuf[c * 2];
            const u32 o2 = mbuf[c * 2 + 1];
            const u32 n1 = umin32(K1[j], o1);
            const u32 n2 = umin32(umax32(K1[j], o1), umin32(K2[j], o2));
            const size_t base = ((size_t)(b * NN + n0 + c) << 3) + mt;
            gk1[base] = n1;
            gk2[base] = n2;
        }
    }
}

// ---------------------------------------------------------------------------
// Fused tail, occupancy-fixed: 32 n-rows/block, grid (64, 8) = 512 blocks
// (2/CU, 2 waves/SIMD vs R13's 1). LDS = embs[32][257] f32 only (~33 KB;
// xs dropped — out phase reads original f32 x directly, coalesced float4
// over n, the R5-proven pattern). Phases: merge (t<32) -> flag -> exact f64
// re-rank (waves over <=32 flagged rows) -> stage emb coalesced -> out.
// Bank audit out-phase embs reads: bank=(4*ng+k+dr)%32 -> exact 2-way = free.
// ---------------------------------------------------------------------------
__global__ __launch_bounds__(256) void tail_kernel(const u32* __restrict__ gk1,
                                                   const u32* __restrict__ gk2,
                                                   const double* __restrict__ sq64,
                                                   const float* __restrict__ x,
                                                   const float* __restrict__ emb,
                                                   float* __restrict__ out) {
    __shared__ float embs[32][257];
    __shared__ int   angs[32];
    __shared__ int   flist[32][3];
    __shared__ int   fcnt;

    const int b  = blockIdx.y;
    const int n0 = blockIdx.x * 32;
    const int t  = threadIdx.x;
    const int w  = t >> 6, l = t & 63;

    if (t == 0) fcnt = 0;
    __syncthreads();

    // ---- 1) per-row slot merge (threads 0..31, one row each) ----
    if (t < 32) {
        const int n = n0 + t;
        const int tg = (b << 11) + n;
        const uint4 a0 = *(const uint4*)&gk1[(size_t)tg << 3];
        const uint4 a1 = *(const uint4*)&gk1[((size_t)tg << 3) + 4];
        const uint4 c0 = *(const uint4*)&gk2[(size_t)tg << 3];
        const uint4 c1 = *(const uint4*)&gk2[((size_t)tg << 3) + 4];
        const u32 ga[8] = {a0.x, a0.y, a0.z, a0.w, a1.x, a1.y, a1.z, a1.w};
        const u32 gc[8] = {c0.x, c0.y, c0.z, c0.w, c1.x, c1.y, c1.z, c1.w};
        u64 k1 = ~0ull, k2 = ~0ull;
#pragma unroll
        for (int s = 0; s < MSPLIT; ++s) {
            const u64 ka = ((u64)(ga[s] >> 8) << 11) | (u32)((s << 8) | (ga[s] & 0xff));
            const u64 kc = ((u64)(gc[s] >> 8) << 11) | (u32)((s << 8) | (gc[s] & 0xff));
            const u64 n1 = umin64(k1, ka);
            const u64 n2 = umin64(umax64(k1, ka), umin64(k2, kc));
            k1 = n1; k2 = n2;
        }
        const int i1 = (int)(k1 & 0x7ff);
        const int i2 = (int)(k2 & 0x7ff);
        const float v1 = __uint_as_float((u32)(k1 >> 11) << 8);
        const float v2 = __uint_as_float((u32)(k2 >> 11) << 8);
        const int a = n - i1;
        angs[t] = a < 0 ? -a : a;
        if (v2 - v1 < 0.25f) {
            const int s = atomicAdd(&fcnt, 1);   // LDS atomic; <= 32 structurally
            flist[s][0] = t; flist[s][1] = i1; flist[s][2] = i2;
        }
    }
    __syncthreads();

    // ---- 2) exact f64 re-rank of flagged rows (one wave per row) ----
    const int nf = fcnt;
    const float* xb = x + (size_t)b * DDIM * NN;
    for (int it = w; it < nf; it += 4) {
        const int rl = flist[it][0], i1 = flist[it][1], i2 = flist[it][2];
        const int n = n0 + rl;
        double d1 = 0.0, d2 = 0.0;
#pragma unroll
        for (int q = 0; q < 4; ++q) {
            const int d = l * 4 + q;
            const double xn = xb[(size_t)d * NN + n];
            d1 += xn * (double)xb[(size_t)d * NN + i1];
            d2 += xn * (double)xb[(size_t)d * NN + i2];
        }
#pragma unroll
        for (int off = 32; off; off >>= 1) {
            d1 += __shfl_down(d1, off);
            d2 += __shfl_down(d2, off);
        }
        if (l == 0) {
            const double sn = sq64[(b << 11) + n];
            double e1 = sn + sq64[(b << 11) + i1] - 2.0 * d1; if (e1 < 0.0) e1 = 0.0;
            double e2 = sn + sq64[(b << 11) + i2] - 2.0 * d2; if (e2 < 0.0) e2 = 0.0;
            const int best = (e2 < e1 || (e2 == e1 && i2 < i1)) ? i2 : i1;
            const int a = n - best;
            angs[rl] = a < 0 ? -a : a;
        }
    }
    __syncthreads();

    // ---- 3a) stage emb rows coalesced (wave w: rows w, w+4, ..., w+28) ----
    for (int rr = w; rr < 32; rr += 4) {
        const int ang = angs[rr];
        const float4 ev = *(const float4*)&emb[(size_t)ang * DDIM + l * 4];
        embs[rr][l * 4]     = ev.x;
        embs[rr][l * 4 + 1] = ev.y;
        embs[rr][l * 4 + 2] = ev.z;
        embs[rr][l * 4 + 3] = ev.w;
    }
    __syncthreads();

    // ---- 3b) output: thread (n-group = t&7 -> 4 n, d = t>>3), 8 d-iters ----
    const int ng = (t & 7) * 4;
    const int dr = t >> 3;
#pragma unroll
    for (int it = 0; it < 8; ++it) {
        const int d = it * 32 + dr;
        const size_t o = ((size_t)b * DDIM + d) * NN + n0 + ng;
        const float4 xv = *(const float4*)&x[o];
        float4 ov;
        ov.x = xv.x + embs[ng][d];
        ov.y = xv.y + embs[ng + 1][d];
        ov.z = xv.z + embs[ng + 2][d];
        ov.w = xv.w + embs[ng + 3][d];
        *(float4*)&out[o] = ov;
    }
}

extern "C" void kernel_launch(void* const* d_in, const int* in_sizes, int n_in,
                              void* d_out, int out_size, void* d_ws, size_t ws_size,
                              hipStream_t stream) {
    const float* x   = (const float*)d_in[0];   // (B, D, N) f32
    const float* emb = (const float*)d_in[1];   // (N, D)    f32
    float* out = (float*)d_out;

    // Workspace carve-up (~9.6 MB total)
    char* ws = (char*)d_ws;
    _Float16* xh   = (_Float16*)ws;                    // 8,388,608 B
    u32*      gk1  = (u32*)(ws + 8388608);             //   524,288 B
    u32*      gk2  = (u32*)(ws + 8912896);             //   524,288 B
    double*   sq64 = (double*)(ws + 9437184);          //   131,072 B
    float*    sqf  = (float*)(ws + 9568256);           //    65,536 B

    // 128 KB dynamic LDS needs the attribute raised (host-side, capture-safe).
    hipFuncSetAttribute(reinterpret_cast<const void*>(gram_topk_kernel),
                        hipFuncAttributeMaxDynamicSharedMemorySize, 131072);

    pre_kernel<<<dim3(32, 8), dim3(256), 0, stream>>>(x, xh, sq64, sqf);
    gram_topk_kernel<<<dim3(512), dim3(512), 131072, stream>>>(xh, sqf, gk1, gk2);
    tail_kernel<<<dim3(64, 8), dim3(256), 0, stream>>>(gk1, gk2, sq64, x, emb, out);
}